// Round 20
// baseline (396.389 us; speedup 1.0000x reference)
//
#include <hip/hip_runtime.h>
#include <math.h>
#include <stdint.h>

// SLAYER 2-layer SNN. Round 32: pin VGPR allocation at 64 (solo change).
//   expand_x -> decompose_i8 x2 ->
//   fused_gc<1024> -> scan<BITS->Bexp2> -> fused_gc<2048> -> scan<F32>.
// R31 post-mortem: LDS 35.8->18.4KB did NOT raise occupancy (39.3->40.1)
// and the f64<->f32 converts cost +12us -> 395.7 regression. The flat
// occupancy identifies the true static limiter: amdgpu_num_vgpr(128) PINS
// the per-wave allocation at 128 (R15: requested==reported), giving
// 512/128 = 4 waves/SIMD regardless of the 60 VGPRs actually used. The
// LDS cap was never binding in R31.
// R32: attribute 128 -> 64. Reported use is 60 <= 64: zero squeeze. At
// 64-VGPR allocation: 8 waves/SIMD; R31's 18.4KB LDS allows the matching
// 8 blocks/CU -> the 2x TLP R31 was designed for, which also hides its
// cvt overhead. Everything else byte-identical to R31.
// Gates: WRITE ~65.5MB (spill -> revert cap AND f32-a_lds); occupancy
// flat -> revert f32-a_lds only (its -12us stands without the payoff).
// absmax 0.0.

#define TT     256
#define KLEN   62
#define THETA  10.0

typedef int v4i __attribute__((ext_vector_type(4)));

// ===================== expand x -> i8 B-matrix (layer 1) ====================
// x: [32][1024][256] f32 {0,1}; bexp: [b][g=i/16][t][m=i%16] i8 {0,1}
__global__ __launch_bounds__(256)
void expand_x(const float* __restrict__ x, signed char* __restrict__ bexp)
{
    const int b = blockIdx.x;
    const int g = blockIdx.y;             // 64 groups of 16 inputs
    const int t = threadIdx.x;
    const float* xp = x + ((size_t)b*1024 + g*16)*TT + t;
    uint32_t uu[4];
    #pragma unroll
    for (int j = 0; j < 4; ++j) {
        uint32_t w = 0;
        #pragma unroll
        for (int m = 0; m < 4; ++m)
            w |= (xp[(size_t)(j*4 + m)*TT] >= 0.5f) ? (1u << (8*m)) : 0u;
        uu[j] = w;
    }
    *(uint4*)(bexp + (((size_t)b*64 + g)*256 + t)*16) = *(const uint4*)uu;
}

// ====================== weight -> int8 digit planes (swizzled) ==============
// planes: [oblk][s(I/64)][p(5)][lane(64)][16 B] -- MFMA A-frag register order:
// lane = quad*16+col holds digits of w[oblk*16+col][s*64 + quad*16 + 0..15].
__global__ __launch_bounds__(256)
void decompose_i8(const float* __restrict__ w, signed char* __restrict__ planes,
                  int I, int total)
{
    const int f = blockIdx.x * 256 + threadIdx.x;
    if (f >= total) return;
    const int NS = I / 64;
    const int per_oblk = NS * 5120;
    int rem  = f;
    const int oblk = rem / per_oblk;  rem -= oblk * per_oblk;
    const int s    = rem / 5120;      rem -= s * 5120;
    const int p    = rem >> 10;
    const int l    = (rem & 1023) >> 4;
    const int j    = rem & 15;
    const int quad = l >> 4, col = l & 15;
    const float wv = w[(size_t)(oblk*16 + col) * I + s*64 + quad*16 + j];
    long long v = llrint((double)wv * 274877906944.0);   // w * 2^38, exact int
    int d = 0;
    for (int q = 0; q <= p; ++q) {                       // balanced base-256
        d = (int)((v + 128) & 255) - 128;
        v = (v - d) >> 8;
    }
    planes[f] = (signed char)d;
}

// ====================== fused gemm+conv kernel ==============================
// grid (B, O/16): b fastest (A-planes L2-hot). Phase 1: single-pass
// acc[5][4] i8 MFMA -> exact fp64 recombine, stored f32 into a_lds
// (swizzled column). Barrier. Phase 2: 61-tap fp64 FIR on f32 a (hoisted
// cols, pinned unroll 2, universal min-clamp). u f32.
// LDS 18.4KB + 64-VGPR allocation -> 8 blocks/CU target.
template<int I>
__global__ __launch_bounds__(256) __attribute__((amdgpu_num_vgpr(64)))
void fused_gc(const signed char* __restrict__ bexp,    // [b][I/16][256][16]
              const signed char* __restrict__ planes,  // swizzled A planes
              float*             __restrict__ u,       // [B][256][OS] f32
              int OS)
{
    constexpr int NS = I / 64;
    __shared__ float  a_lds[257 * 17];                   // 17.5 KB (row 256 = 0)
    __shared__ double srmE[68];

    const int tid  = threadIdx.x;
    const int lane = tid & 63;
    const int wvu  = tid >> 6;
    const int quad = lane >> 4;
    const int col  = lane & 15;
    const int b    = blockIdx.x;
    const int oblk = blockIdx.y;
    const int o0   = oblk * 16;
    const int tw   = wvu * 64;

    if (tid < 68) {
        const int k = tid - 2;
        double v = 0.0;
        if (k >= 1 && k <= 61) {
            double wv = (double)k / 8.0 * exp(1.0 - (double)k / 8.0);
            v = (double)(float)wv;     // fp32-rounded tap, widened (R1-R31)
        }
        srmE[tid] = v;
    }

    // ---------------- phase 1: merged gemm (single K-loop, R26) -------------
    const signed char* Apg = planes + (size_t)oblk * NS * 5120 + lane * 16;
    const signed char* Bx  = bexp + (((size_t)b*(I/16) + quad)*256 + tw + col)*16;
    const double inv = 1.0 / 274877906944.0;             // 2^-38

    v4i acc[5][4];
    #pragma unroll
    for (int p = 0; p < 5; ++p)
        #pragma unroll
        for (int nt = 0; nt < 4; ++nt)
            acc[p][nt] = (v4i){0, 0, 0, 0};

    #pragma unroll 1
    for (int s = 0; s < NS; ++s) {
        v4i af[5];
        #pragma unroll
        for (int p = 0; p < 5; ++p)
            af[p] = *(const v4i*)(const void*)(Apg + (size_t)s * 5120 + p * 1024);
        v4i bf[4];
        #pragma unroll
        for (int nt = 0; nt < 4; ++nt)
            bf[nt] = *(const v4i*)(const void*)(Bx + (size_t)s * 16384 + nt * 256);

        #pragma unroll
        for (int nt = 0; nt < 4; ++nt)
            #pragma unroll
            for (int p = 0; p < 5; ++p)
                acc[p][nt] = __builtin_amdgcn_mfma_i32_16x16x64_i8(
                                 af[p], bf[nt], acc[p][nt], 0, 0, 0);
    }

    // recombine: exact fp64 -> f32 a into LDS at swizzled column -------------
    #pragma unroll
    for (int nt = 0; nt < 4; ++nt) {
        const int t = tw + nt*16 + col;
        const int cb = quad*4 + ((t & 3) << 2);          // wrap-free base
        #pragma unroll
        for (int r = 0; r < 4; ++r) {
            double v =            (double)acc[4][nt][r];
            v = v * 256.0 + (double)acc[3][nt][r];
            v = v * 256.0 + (double)acc[2][nt][r];
            v = v * 256.0 + (double)acc[1][nt][r];
            v = v * 256.0 + (double)acc[0][nt][r];
            a_lds[t * 17 + ((cb + r) & 15)] = (float)(v * inv);
        }
    }

    if (tid < 17) a_lds[256 * 17 + tid] = 0.0f;          // zero-guard row
    __syncthreads();                                     // the only barrier

    // ---------------- phase 2: conv (hoisted cols, pinned unroll) -----------
    const int o    = tid & 15;
    const int tgrp = tid >> 4;                           // 0..15
    // row%4 invariant (T0b%4==0, d%4==0, -61%4==3): slot k reads row==3+k
    // (mod 4) -> column per slot is a per-thread constant. Clamped row 256
    // reads co0 -- zeroed, identical.
    const int co0 = (o + 12) & 15;
    const int co1 = o;
    const int co2 = (o + 4) & 15;
    const int co3 = (o + 8) & 15;

    #pragma unroll 1
    for (int pass = 0; pass < 4; ++pass) {
        const int T0b = pass * 64 + tgrp * 4;
        double u0 = 0, u1 = 0, u2 = 0, u3 = 0;
        double w1 = srmE[64], w2 = srmE[65], w3 = srmE[66];   // zero pads
        #pragma unroll 2
        for (int d = 0; d < 64; d += 4) {
            const int row = T0b - 61 + d;
            const unsigned r0 = min((unsigned)(row + 0), 256u);
            const unsigned r1 = min((unsigned)(row + 1), 256u);
            const unsigned r2 = min((unsigned)(row + 2), 256u);
            const unsigned r3 = min((unsigned)(row + 3), 256u);
            const double av0 = (double)a_lds[r0 * 17 + co0];
            const double av1 = (double)a_lds[r1 * 17 + co1];
            const double av2 = (double)a_lds[r2 * 17 + co2];
            const double av3 = (double)a_lds[r3 * 17 + co3];
            const double n0 = srmE[63 - d], n1 = srmE[62 - d];
            const double n2 = srmE[61 - d], n3 = srmE[60 - d];
            u0 = fma(n0, av0, u0); u1 = fma(w1, av0, u1); u2 = fma(w2, av0, u2); u3 = fma(w3, av0, u3);
            u0 = fma(n1, av1, u0); u1 = fma(n0, av1, u1); u2 = fma(w1, av1, u2); u3 = fma(w2, av1, u3);
            u0 = fma(n2, av2, u0); u1 = fma(n1, av2, u1); u2 = fma(n0, av2, u2); u3 = fma(w1, av2, u3);
            u0 = fma(n3, av3, u0); u1 = fma(n2, av3, u1); u2 = fma(n1, av3, u2); u3 = fma(n0, av3, u3);
            w1 = n3; w2 = n2; w3 = n1;
        }
        float* up = u + ((size_t)b * 256 + T0b) * OS + o0 + o;
        up[0]              = (float)u0;
        up[(size_t)OS]     = (float)u1;
        up[(size_t)OS * 2] = (float)u2;
        up[(size_t)OS * 3] = (float)u3;
    }
}

// ========================== scan (byte-table refractory) ====================
// lane = neuron; 256 sequential steps. Refractory via 8 independent LDS
// table lookups; u read as f32, promoted to fp64 for the threshold.
// 16-t prefetch pipeline (R26/R28-proven).
// FINAL=false: 256-thread blocks; ballots -> expanded i8 bexp_out.
// FINAL=true:  64-thread blocks, grid (8,32) -> all CUs; f32 out[b][o][t].
template<bool FINAL>
__global__ void scan_spikes(const float* __restrict__ u,
                            signed char* __restrict__ bexp_out,
                            float* __restrict__ f32_out, int OS)
{
    __shared__ double   ref64[KLEN];
    __shared__ double   tbl[8 * 256];   // 16 KB byte-sum tables
    __shared__ uint32_t blds[8][256];   // 8 KB ballot staging
    const int tid  = threadIdx.x;
    const int nthr = FINAL ? 64 : 256;

    if (tid < KLEN) {
        double v = (double)tid / 8.0 * exp(1.0 - (double)tid / 8.0);
        ref64[tid] = (double)(float)(-20.0 * v);
    }
    __syncthreads();
    for (int e = tid; e < 2048; e += nthr) {
        const int j = e >> 8, v = e & 255;
        double s = 0.0;
        #pragma unroll
        for (int i = 0; i < 8; ++i) {
            const int k = j * 8 + i + 1;
            if (k <= 61)
                s += ((v >> i) & 1) ? ref64[k] : 0.0;
        }
        tbl[e] = s;
    }
    __syncthreads();

    const int b     = blockIdx.y;
    const int obase = blockIdx.x * nthr;
    const int o     = obase + tid;
    const int lane  = tid & 63;
    const int wv    = tid >> 6;
    const float* up = u + (size_t)b * TT * OS + o;

    uint64_t mask = 0;
    // 3-stage prefetch: c = current 8 t, d = next 8 t; n issued in-loop
    float c0 = up[0],            c1 = up[OS],
          c2 = up[2*(size_t)OS], c3 = up[3*(size_t)OS],
          c4 = up[4*(size_t)OS], c5 = up[5*(size_t)OS],
          c6 = up[6*(size_t)OS], c7 = up[7*(size_t)OS];
    float d0 = up[ 8*(size_t)OS], d1 = up[ 9*(size_t)OS],
          d2 = up[10*(size_t)OS], d3 = up[11*(size_t)OS],
          d4 = up[12*(size_t)OS], d5 = up[13*(size_t)OS],
          d6 = up[14*(size_t)OS], d7 = up[15*(size_t)OS];
    for (int t0 = 0; t0 < TT; t0 += 8) {
        float n0 = 0, n1 = 0, n2 = 0, n3 = 0, n4 = 0, n5 = 0, n6 = 0, n7 = 0;
        if (t0 + 16 < TT) {
            const float* pp = up + (size_t)(t0 + 16) * OS;
            n0 = pp[0];            n1 = pp[OS];
            n2 = pp[2*(size_t)OS]; n3 = pp[3*(size_t)OS];
            n4 = pp[4*(size_t)OS]; n5 = pp[5*(size_t)OS];
            n6 = pp[6*(size_t)OS]; n7 = pp[7*(size_t)OS];
        }
        #pragma unroll
        for (int q = 0; q < 8; ++q) {
            const float uvf = (q == 0) ? c0 : (q == 1) ? c1 : (q == 2) ? c2 :
                              (q == 3) ? c3 : (q == 4) ? c4 : (q == 5) ? c5 :
                              (q == 6) ? c6 : c7;
            const uint64_t m = mask;
            const double ra = tbl[        (int)( m        & 255)]
                            + tbl[256   + (int)((m >>  8) & 255)];
            const double rb = tbl[512   + (int)((m >> 16) & 255)]
                            + tbl[768   + (int)((m >> 24) & 255)];
            const double rc = tbl[1024  + (int)((m >> 32) & 255)]
                            + tbl[1280  + (int)((m >> 40) & 255)];
            const double rd = tbl[1536  + (int)((m >> 48) & 255)]
                            + tbl[1792  + (int)((m >> 56) & 255)];
            const double r  = (ra + rb) + (rc + rd);
            const bool s = ((double)uvf + r) >= THETA;
            const uint64_t bal = __ballot(s);
            if (lane == 0) {
                blds[wv * 2 + 0][t0 + q] = (uint32_t)bal;
                blds[wv * 2 + 1][t0 + q] = (uint32_t)(bal >> 32);
            }
            mask = ((mask << 1) | (s ? 1ull : 0ull)) & ((1ull << 61) - 1ull);
        }
        c0 = d0; c1 = d1; c2 = d2; c3 = d3; c4 = d4; c5 = d5; c6 = d6; c7 = d7;
        d0 = n0; d1 = n1; d2 = n2; d3 = n3; d4 = n4; d5 = n5; d6 = n6; d7 = n7;
    }
    __syncthreads();

    if (!FINAL) {
        // expand ballots to i8 B-matrix: entry g = obase/16 + gl, byte m =
        // bit ((gl&1)*16 + m) of word blds[gl>>1][t]  (i = g*16 + m)
        const int gbase = obase >> 4;
        for (int e = tid; e < 16 * 256; e += 256) {
            const int gl = e >> 8, t = e & 255;
            const uint32_t w = blds[gl >> 1][t];
            const uint32_t h = (w >> ((gl & 1) * 16)) & 0xFFFFu;
            uint32_t uu[4];
            #pragma unroll
            for (int j = 0; j < 4; ++j)
                uu[j] = (((h >> (4*j)) & 0xFu) * 0x00204081u) & 0x01010101u;
            *(uint4*)(bexp_out + (((size_t)b*128 + gbase + gl)*256 + t)*16) =
                *(const uint4*)uu;
        }
    } else {
        // 64-thread blocks: 64 neurons x 256 t, coalesced 256B rows
        for (int e = tid; e < 64 * 256; e += 64) {
            const int ol = e >> 8, tq = e & 255;
            const uint32_t w = blds[ol >> 5][tq];
            f32_out[((size_t)b * 512 + obase + ol) * TT + tq] =
                (float)((w >> (ol & 31)) & 1u);
        }
    }
}

// ================================ launcher ==================================
extern "C" void kernel_launch(void* const* d_in, const int* in_sizes, int n_in,
                              void* d_out, int out_size, void* d_ws, size_t ws_size,
                              hipStream_t stream)
{
    const float* x  = (const float*)d_in[0];   // [32][1024][256]
    const float* w1 = (const float*)d_in[1];   // [2048][1024]
    const float* w2 = (const float*)d_in[2];   // [512][2048]
    float* out = (float*)d_out;                // [32][512][256]

    char* ws = (char*)d_ws;
    // liveness-based layout (Bexp2 aliases dead P1/Bexp1); u f32 (67 MB)
    signed char* P2    = (signed char*)ws;                      // 5.25 MB
    size_t roff = (size_t)32 * 32 * 5120;                       // 5242880
    signed char* P1    = (signed char*)(ws + roff);             // 10.5 MB
    signed char* Bexp1 = (signed char*)(ws + roff + (size_t)128*16*5120); // 8 MB
    signed char* Bexp2 = (signed char*)(ws + roff);             // 16 MB (alias)
    size_t uoff = roff + (size_t)128*16*5120 + (size_t)32*64*256*16; // 24117248
    float* uBuf = (float*)(ws + uoff);                          // 67 MB f32

    expand_x<<<dim3(32, 64), 256, 0, stream>>>(x, Bexp1);
    decompose_i8<<<dim3((10485760 + 255)/256), 256, 0, stream>>>(w1, P1, 1024, 10485760);
    decompose_i8<<<dim3((5242880  + 255)/256), 256, 0, stream>>>(w2, P2, 2048, 5242880);

    // layer 1: 1024 -> 2048  (fused gemm+conv: u written directly, f32)
    fused_gc<1024><<<dim3(32, 128), 256, 0, stream>>>(Bexp1, P1, uBuf, 2048);
    scan_spikes<false><<<dim3(8, 32), 256, 0, stream>>>(uBuf, Bexp2, nullptr, 2048);
    // layer 2: 2048 -> 512
    fused_gc<2048><<<dim3(32, 32), 256, 0, stream>>>(Bexp2, P2, uBuf, 512);
    scan_spikes<true><<<dim3(8, 32), 64, 0, stream>>>(uBuf, nullptr, out, 512);
}

// Round 21
// 382.984 us; speedup vs baseline: 1.0350x; 1.0350x over previous
//
#include <hip/hip_runtime.h>
#include <math.h>
#include <stdint.h>

// SLAYER 2-layer SNN. Round 33: all-f32 conv FIR (solo numeric-width change).
//   expand_x -> decompose_i8 x2 ->
//   fused_gc<1024> -> scan<BITS->Bexp2> -> fused_gc<2048> -> scan<F32>.
// R32 post-mortem: 64-VGPR attr did NOT raise occupancy (40.9 vs 40.1) ->
// limiter is the UNIFIED VGPR+AGPR file: acc[5][4] = 80 AGPRs invisible to
// the attr and to VGPR_Count; true total ~150/wave -> 3 waves/SIMD ~ 40%.
// Occupancy structurally pinned for merged gemm. Pivot to issue-boundedness
// (Mfma 27 + VALU 63 = 90%): conv does 4096 fp64 FMA/thread at quarter
// rate (~54us/SIMD of the ~80us VALU issue) + R31's converts.
// R33: conv entirely f32. Taps were fp32-rounded since R1 (same values);
// only change = f32 accumulation (~1e-5 abs), the band already tolerated
// by f32-u (R28) and by the reference's own f32 conv. f32 a_lds (R31/R32,
// absmax 0.0 proven) now pays: no converts, f32 FMA at full rate.
// Structure untouched: hoisted cols, min-clamp, unroll-2 pin, 64-cap.
// Gates: WRITE ~65.5MB, VGPR <= 64, absmax 0.0 (flip -> revert to R30
// wholesale: fp64 a_lds + fp64 conv).

#define TT     256
#define KLEN   62
#define THETA  10.0

typedef int v4i __attribute__((ext_vector_type(4)));

// ===================== expand x -> i8 B-matrix (layer 1) ====================
// x: [32][1024][256] f32 {0,1}; bexp: [b][g=i/16][t][m=i%16] i8 {0,1}
__global__ __launch_bounds__(256)
void expand_x(const float* __restrict__ x, signed char* __restrict__ bexp)
{
    const int b = blockIdx.x;
    const int g = blockIdx.y;             // 64 groups of 16 inputs
    const int t = threadIdx.x;
    const float* xp = x + ((size_t)b*1024 + g*16)*TT + t;
    uint32_t uu[4];
    #pragma unroll
    for (int j = 0; j < 4; ++j) {
        uint32_t w = 0;
        #pragma unroll
        for (int m = 0; m < 4; ++m)
            w |= (xp[(size_t)(j*4 + m)*TT] >= 0.5f) ? (1u << (8*m)) : 0u;
        uu[j] = w;
    }
    *(uint4*)(bexp + (((size_t)b*64 + g)*256 + t)*16) = *(const uint4*)uu;
}

// ====================== weight -> int8 digit planes (swizzled) ==============
// planes: [oblk][s(I/64)][p(5)][lane(64)][16 B] -- MFMA A-frag register order:
// lane = quad*16+col holds digits of w[oblk*16+col][s*64 + quad*16 + 0..15].
__global__ __launch_bounds__(256)
void decompose_i8(const float* __restrict__ w, signed char* __restrict__ planes,
                  int I, int total)
{
    const int f = blockIdx.x * 256 + threadIdx.x;
    if (f >= total) return;
    const int NS = I / 64;
    const int per_oblk = NS * 5120;
    int rem  = f;
    const int oblk = rem / per_oblk;  rem -= oblk * per_oblk;
    const int s    = rem / 5120;      rem -= s * 5120;
    const int p    = rem >> 10;
    const int l    = (rem & 1023) >> 4;
    const int j    = rem & 15;
    const int quad = l >> 4, col = l & 15;
    const float wv = w[(size_t)(oblk*16 + col) * I + s*64 + quad*16 + j];
    long long v = llrint((double)wv * 274877906944.0);   // w * 2^38, exact int
    int d = 0;
    for (int q = 0; q <= p; ++q) {                       // balanced base-256
        d = (int)((v + 128) & 255) - 128;
        v = (v - d) >> 8;
    }
    planes[f] = (signed char)d;
}

// ====================== fused gemm+conv kernel ==============================
// grid (B, O/16): b fastest (A-planes L2-hot). Phase 1: single-pass
// acc[5][4] i8 MFMA -> exact fp64 recombine, stored f32 into a_lds
// (swizzled column). Barrier. Phase 2: 61-tap f32 FIR (full-rate FMA, no
// converts; hoisted cols, pinned unroll 2, universal min-clamp). u f32.
template<int I>
__global__ __launch_bounds__(256) __attribute__((amdgpu_num_vgpr(64)))
void fused_gc(const signed char* __restrict__ bexp,    // [b][I/16][256][16]
              const signed char* __restrict__ planes,  // swizzled A planes
              float*             __restrict__ u,       // [B][256][OS] f32
              int OS)
{
    constexpr int NS = I / 64;
    __shared__ float a_lds[257 * 17];                    // 17.5 KB (row 256 = 0)
    __shared__ float srm32[68];

    const int tid  = threadIdx.x;
    const int lane = tid & 63;
    const int wvu  = tid >> 6;
    const int quad = lane >> 4;
    const int col  = lane & 15;
    const int b    = blockIdx.x;
    const int oblk = blockIdx.y;
    const int o0   = oblk * 16;
    const int tw   = wvu * 64;

    if (tid < 68) {
        const int k = tid - 2;
        double wv = 0.0;
        if (k >= 1 && k <= 61)
            wv = (double)k / 8.0 * exp(1.0 - (double)k / 8.0);
        srm32[tid] = (float)wv;        // same fp32-rounded taps as R1-R32
    }

    // ---------------- phase 1: merged gemm (single K-loop, R26) -------------
    const signed char* Apg = planes + (size_t)oblk * NS * 5120 + lane * 16;
    const signed char* Bx  = bexp + (((size_t)b*(I/16) + quad)*256 + tw + col)*16;
    const double inv = 1.0 / 274877906944.0;             // 2^-38

    v4i acc[5][4];
    #pragma unroll
    for (int p = 0; p < 5; ++p)
        #pragma unroll
        for (int nt = 0; nt < 4; ++nt)
            acc[p][nt] = (v4i){0, 0, 0, 0};

    #pragma unroll 1
    for (int s = 0; s < NS; ++s) {
        v4i af[5];
        #pragma unroll
        for (int p = 0; p < 5; ++p)
            af[p] = *(const v4i*)(const void*)(Apg + (size_t)s * 5120 + p * 1024);
        v4i bf[4];
        #pragma unroll
        for (int nt = 0; nt < 4; ++nt)
            bf[nt] = *(const v4i*)(const void*)(Bx + (size_t)s * 16384 + nt * 256);

        #pragma unroll
        for (int nt = 0; nt < 4; ++nt)
            #pragma unroll
            for (int p = 0; p < 5; ++p)
                acc[p][nt] = __builtin_amdgcn_mfma_i32_16x16x64_i8(
                                 af[p], bf[nt], acc[p][nt], 0, 0, 0);
    }

    // recombine: exact fp64 -> f32 a into LDS at swizzled column -------------
    #pragma unroll
    for (int nt = 0; nt < 4; ++nt) {
        const int t = tw + nt*16 + col;
        const int cb = quad*4 + ((t & 3) << 2);          // wrap-free base
        #pragma unroll
        for (int r = 0; r < 4; ++r) {
            double v =            (double)acc[4][nt][r];
            v = v * 256.0 + (double)acc[3][nt][r];
            v = v * 256.0 + (double)acc[2][nt][r];
            v = v * 256.0 + (double)acc[1][nt][r];
            v = v * 256.0 + (double)acc[0][nt][r];
            a_lds[t * 17 + ((cb + r) & 15)] = (float)(v * inv);
        }
    }

    if (tid < 17) a_lds[256 * 17 + tid] = 0.0f;          // zero-guard row
    __syncthreads();                                     // the only barrier

    // ---------------- phase 2: conv, all f32 (hoisted cols, pinned) ---------
    const int o    = tid & 15;
    const int tgrp = tid >> 4;                           // 0..15
    // row%4 invariant (T0b%4==0, d%4==0, -61%4==3): slot k reads row==3+k
    // (mod 4) -> column per slot is a per-thread constant. Clamped row 256
    // reads co0 -- zeroed, identical.
    const int co0 = (o + 12) & 15;
    const int co1 = o;
    const int co2 = (o + 4) & 15;
    const int co3 = (o + 8) & 15;

    #pragma unroll 1
    for (int pass = 0; pass < 4; ++pass) {
        const int T0b = pass * 64 + tgrp * 4;
        float u0 = 0.f, u1 = 0.f, u2 = 0.f, u3 = 0.f;
        float w1 = srm32[64], w2 = srm32[65], w3 = srm32[66];  // zero pads
        #pragma unroll 2
        for (int d = 0; d < 64; d += 4) {
            const int row = T0b - 61 + d;
            const unsigned r0 = min((unsigned)(row + 0), 256u);
            const unsigned r1 = min((unsigned)(row + 1), 256u);
            const unsigned r2 = min((unsigned)(row + 2), 256u);
            const unsigned r3 = min((unsigned)(row + 3), 256u);
            const float av0 = a_lds[r0 * 17 + co0];
            const float av1 = a_lds[r1 * 17 + co1];
            const float av2 = a_lds[r2 * 17 + co2];
            const float av3 = a_lds[r3 * 17 + co3];
            const float n0 = srm32[63 - d], n1 = srm32[62 - d];
            const float n2 = srm32[61 - d], n3 = srm32[60 - d];
            u0 = fmaf(n0, av0, u0); u1 = fmaf(w1, av0, u1); u2 = fmaf(w2, av0, u2); u3 = fmaf(w3, av0, u3);
            u0 = fmaf(n1, av1, u0); u1 = fmaf(n0, av1, u1); u2 = fmaf(w1, av1, u2); u3 = fmaf(w2, av1, u3);
            u0 = fmaf(n2, av2, u0); u1 = fmaf(n1, av2, u1); u2 = fmaf(n0, av2, u2); u3 = fmaf(w1, av2, u3);
            u0 = fmaf(n3, av3, u0); u1 = fmaf(n2, av3, u1); u2 = fmaf(n1, av3, u2); u3 = fmaf(n0, av3, u3);
            w1 = n3; w2 = n2; w3 = n1;
        }
        float* up = u + ((size_t)b * 256 + T0b) * OS + o0 + o;
        up[0]              = u0;
        up[(size_t)OS]     = u1;
        up[(size_t)OS * 2] = u2;
        up[(size_t)OS * 3] = u3;
    }
}

// ========================== scan (byte-table refractory) ====================
// lane = neuron; 256 sequential steps. Refractory via 8 independent LDS
// table lookups; u read as f32, promoted to fp64 for the threshold.
// 16-t prefetch pipeline (R26/R28-proven).
// FINAL=false: 256-thread blocks; ballots -> expanded i8 bexp_out.
// FINAL=true:  64-thread blocks, grid (8,32) -> all CUs; f32 out[b][o][t].
template<bool FINAL>
__global__ void scan_spikes(const float* __restrict__ u,
                            signed char* __restrict__ bexp_out,
                            float* __restrict__ f32_out, int OS)
{
    __shared__ double   ref64[KLEN];
    __shared__ double   tbl[8 * 256];   // 16 KB byte-sum tables
    __shared__ uint32_t blds[8][256];   // 8 KB ballot staging
    const int tid  = threadIdx.x;
    const int nthr = FINAL ? 64 : 256;

    if (tid < KLEN) {
        double v = (double)tid / 8.0 * exp(1.0 - (double)tid / 8.0);
        ref64[tid] = (double)(float)(-20.0 * v);
    }
    __syncthreads();
    for (int e = tid; e < 2048; e += nthr) {
        const int j = e >> 8, v = e & 255;
        double s = 0.0;
        #pragma unroll
        for (int i = 0; i < 8; ++i) {
            const int k = j * 8 + i + 1;
            if (k <= 61)
                s += ((v >> i) & 1) ? ref64[k] : 0.0;
        }
        tbl[e] = s;
    }
    __syncthreads();

    const int b     = blockIdx.y;
    const int obase = blockIdx.x * nthr;
    const int o     = obase + tid;
    const int lane  = tid & 63;
    const int wv    = tid >> 6;
    const float* up = u + (size_t)b * TT * OS + o;

    uint64_t mask = 0;
    // 3-stage prefetch: c = current 8 t, d = next 8 t; n issued in-loop
    float c0 = up[0],            c1 = up[OS],
          c2 = up[2*(size_t)OS], c3 = up[3*(size_t)OS],
          c4 = up[4*(size_t)OS], c5 = up[5*(size_t)OS],
          c6 = up[6*(size_t)OS], c7 = up[7*(size_t)OS];
    float d0 = up[ 8*(size_t)OS], d1 = up[ 9*(size_t)OS],
          d2 = up[10*(size_t)OS], d3 = up[11*(size_t)OS],
          d4 = up[12*(size_t)OS], d5 = up[13*(size_t)OS],
          d6 = up[14*(size_t)OS], d7 = up[15*(size_t)OS];
    for (int t0 = 0; t0 < TT; t0 += 8) {
        float n0 = 0, n1 = 0, n2 = 0, n3 = 0, n4 = 0, n5 = 0, n6 = 0, n7 = 0;
        if (t0 + 16 < TT) {
            const float* pp = up + (size_t)(t0 + 16) * OS;
            n0 = pp[0];            n1 = pp[OS];
            n2 = pp[2*(size_t)OS]; n3 = pp[3*(size_t)OS];
            n4 = pp[4*(size_t)OS]; n5 = pp[5*(size_t)OS];
            n6 = pp[6*(size_t)OS]; n7 = pp[7*(size_t)OS];
        }
        #pragma unroll
        for (int q = 0; q < 8; ++q) {
            const float uvf = (q == 0) ? c0 : (q == 1) ? c1 : (q == 2) ? c2 :
                              (q == 3) ? c3 : (q == 4) ? c4 : (q == 5) ? c5 :
                              (q == 6) ? c6 : c7;
            const uint64_t m = mask;
            const double ra = tbl[        (int)( m        & 255)]
                            + tbl[256   + (int)((m >>  8) & 255)];
            const double rb = tbl[512   + (int)((m >> 16) & 255)]
                            + tbl[768   + (int)((m >> 24) & 255)];
            const double rc = tbl[1024  + (int)((m >> 32) & 255)]
                            + tbl[1280  + (int)((m >> 40) & 255)];
            const double rd = tbl[1536  + (int)((m >> 48) & 255)]
                            + tbl[1792  + (int)((m >> 56) & 255)];
            const double r  = (ra + rb) + (rc + rd);
            const bool s = ((double)uvf + r) >= THETA;
            const uint64_t bal = __ballot(s);
            if (lane == 0) {
                blds[wv * 2 + 0][t0 + q] = (uint32_t)bal;
                blds[wv * 2 + 1][t0 + q] = (uint32_t)(bal >> 32);
            }
            mask = ((mask << 1) | (s ? 1ull : 0ull)) & ((1ull << 61) - 1ull);
        }
        c0 = d0; c1 = d1; c2 = d2; c3 = d3; c4 = d4; c5 = d5; c6 = d6; c7 = d7;
        d0 = n0; d1 = n1; d2 = n2; d3 = n3; d4 = n4; d5 = n5; d6 = n6; d7 = n7;
    }
    __syncthreads();

    if (!FINAL) {
        // expand ballots to i8 B-matrix: entry g = obase/16 + gl, byte m =
        // bit ((gl&1)*16 + m) of word blds[gl>>1][t]  (i = g*16 + m)
        const int gbase = obase >> 4;
        for (int e = tid; e < 16 * 256; e += 256) {
            const int gl = e >> 8, t = e & 255;
            const uint32_t w = blds[gl >> 1][t];
            const uint32_t h = (w >> ((gl & 1) * 16)) & 0xFFFFu;
            uint32_t uu[4];
            #pragma unroll
            for (int j = 0; j < 4; ++j)
                uu[j] = (((h >> (4*j)) & 0xFu) * 0x00204081u) & 0x01010101u;
            *(uint4*)(bexp_out + (((size_t)b*128 + gbase + gl)*256 + t)*16) =
                *(const uint4*)uu;
        }
    } else {
        // 64-thread blocks: 64 neurons x 256 t, coalesced 256B rows
        for (int e = tid; e < 64 * 256; e += 64) {
            const int ol = e >> 8, tq = e & 255;
            const uint32_t w = blds[ol >> 5][tq];
            f32_out[((size_t)b * 512 + obase + ol) * TT + tq] =
                (float)((w >> (ol & 31)) & 1u);
        }
    }
}

// ================================ launcher ==================================
extern "C" void kernel_launch(void* const* d_in, const int* in_sizes, int n_in,
                              void* d_out, int out_size, void* d_ws, size_t ws_size,
                              hipStream_t stream)
{
    const float* x  = (const float*)d_in[0];   // [32][1024][256]
    const float* w1 = (const float*)d_in[1];   // [2048][1024]
    const float* w2 = (const float*)d_in[2];   // [512][2048]
    float* out = (float*)d_out;                // [32][512][256]

    char* ws = (char*)d_ws;
    // liveness-based layout (Bexp2 aliases dead P1/Bexp1); u f32 (67 MB)
    signed char* P2    = (signed char*)ws;                      // 5.25 MB
    size_t roff = (size_t)32 * 32 * 5120;                       // 5242880
    signed char* P1    = (signed char*)(ws + roff);             // 10.5 MB
    signed char* Bexp1 = (signed char*)(ws + roff + (size_t)128*16*5120); // 8 MB
    signed char* Bexp2 = (signed char*)(ws + roff);             // 16 MB (alias)
    size_t uoff = roff + (size_t)128*16*5120 + (size_t)32*64*256*16; // 24117248
    float* uBuf = (float*)(ws + uoff);                          // 67 MB f32

    expand_x<<<dim3(32, 64), 256, 0, stream>>>(x, Bexp1);
    decompose_i8<<<dim3((10485760 + 255)/256), 256, 0, stream>>>(w1, P1, 1024, 10485760);
    decompose_i8<<<dim3((5242880  + 255)/256), 256, 0, stream>>>(w2, P2, 2048, 5242880);

    // layer 1: 1024 -> 2048  (fused gemm+conv: u written directly, f32)
    fused_gc<1024><<<dim3(32, 128), 256, 0, stream>>>(Bexp1, P1, uBuf, 2048);
    scan_spikes<false><<<dim3(8, 32), 256, 0, stream>>>(uBuf, Bexp2, nullptr, 2048);
    // layer 2: 2048 -> 512
    fused_gc<2048><<<dim3(32, 32), 256, 0, stream>>>(Bexp2, P2, uBuf, 512);
    scan_spikes<true><<<dim3(8, 32), 64, 0, stream>>>(uBuf, nullptr, out, 512);
}